// Round 1
// baseline (1848.476 us; speedup 1.0000x reference)
//
#include <hip/hip_runtime.h>
#include <hip/hip_bf16.h>

#define B_ 32
#define S_ 201
#define SL 200
#define H_ 512
#define V_ 32000
#define M_ (B_*SL)   // 6400

typedef unsigned short u16;
typedef __bf16 bf16x8 __attribute__((ext_vector_type(8)));
typedef float f32x4 __attribute__((ext_vector_type(4)));

__device__ __forceinline__ u16 f2b(float x){
  __hip_bfloat16 h = __float2bfloat16(x);
  union U { __hip_bfloat16 h; u16 u; } c; c.h = h; return c.u;
}
__device__ __forceinline__ float eluf(float x){ return x > 0.f ? x : expm1f(x); }
__device__ __forceinline__ float sigm(float x){ return 1.f/(1.f+expf(-x)); }

// ---------------- lens + rowmask ----------------
__global__ __launch_bounds__(256) void k_lens(const int* __restrict__ cas,
                                              int* __restrict__ lens,
                                              float* __restrict__ rowmask){
  int b = blockIdx.x, t = threadIdx.x;
  int v = 0;
  if (t < SL) v = (cas[b*S_ + t] != 0) ? 1 : 0;
  unsigned long long m = __ballot(v);
  int wsum = __popcll(m);
  __shared__ int ws4[4];
  if ((t & 63) == 0) ws4[t >> 6] = wsum;
  __syncthreads();
  int len = ws4[0] + ws4[1] + ws4[2] + ws4[3];
  if (t == 0) lens[b] = len;
  if (t < SL) rowmask[b*SL + t] = (t < len) ? 1.f : 0.f;
}

// ---------------- gather rows -> bf16 ----------------
__global__ __launch_bounds__(256) void k_gather(const float* __restrict__ table,
                                                const int* __restrict__ idx,
                                                u16* __restrict__ out){
  int r = blockIdx.x, t = threadIdx.x;
  int b = r / SL, s = r % SL;
  int tok = idx[b*S_ + s];
  const float* src = table + (size_t)tok * H_;
  u16* dst = out + (size_t)r * H_;
  dst[t]       = f2b(src[t]);
  dst[t + 256] = f2b(src[t + 256]);
}

// ---------------- transpose f32 (K x N) -> bf16 (N x K) ----------------
__global__ void k_transpose(const float* __restrict__ W, u16* __restrict__ WT,
                            int K, int N){
  __shared__ float tile[32][33];
  int n0 = blockIdx.x*32, k0 = blockIdx.y*32;
  int tx = threadIdx.x, ty = threadIdx.y;  // (32, 8)
  #pragma unroll
  for (int i = 0; i < 4; i++)
    tile[ty + i*8][tx] = W[(size_t)(k0 + ty + i*8)*N + n0 + tx];
  __syncthreads();
  #pragma unroll
  for (int i = 0; i < 4; i++)
    WT[(size_t)(n0 + ty + i*8)*K + k0 + tx] = f2b(tile[tx][ty + i*8]);
}

// ---------------- bf16 MFMA GEMM: C(MxN) = A(MxK) * BT(NxK)^T ----------------
#define EPI_PLAIN 0
#define EPI_HID 1
#define EPI_GATE 2
#define EPI_ELU 3
#define EPI_ELUMUL 4

#define BM 128
#define BN 128
#define BK 64
#define LDSS 72

template<int EPI>
__global__ __launch_bounds__(256) void k_gemm(
    const u16* __restrict__ A, const u16* __restrict__ BT,
    int tiles_n, int tiles_m, int N, int K,
    const float* __restrict__ bias,
    float* __restrict__ outF, u16* __restrict__ outB,
    const float* __restrict__ aux1, const float* __restrict__ auxCh,
    const float* __restrict__ auxDep, const float* __restrict__ rowmask)
{
  __shared__ __align__(16) u16 As[BM*LDSS];
  __shared__ __align__(16) u16 Bs[BN*LDSS];

  // supertile swizzle (GM row-tiles share a B column band for L2 reuse)
  const int GM = 8;
  int bid = blockIdx.x;
  int group = GM * tiles_n;
  int g = bid / group, rem = bid % group;
  int gm = min(GM, tiles_m - g*GM);
  int bm0 = (g*GM + rem % gm) * BM;
  int bn0 = (rem / gm) * BN;

  int tid = threadIdx.x;
  int lane = tid & 63, wave = tid >> 6;
  int wm = (wave >> 1) * 64, wn = (wave & 1) * 64;

  f32x4 acc[4][4] = {};

  int srow = tid >> 1;
  int skb  = (tid & 1) * 32;
  const u16* ga = A  + (size_t)(bm0 + srow) * K + skb;
  const u16* gb = BT + (size_t)(bn0 + srow) * K + skb;
  u16* sa = As + srow * LDSS + skb;
  u16* sb = Bs + srow * LDSS + skb;

  for (int k0 = 0; k0 < K; k0 += BK) {
    {
      const int4* pa = (const int4*)(ga + k0);
      const int4* pb = (const int4*)(gb + k0);
      int4 a0 = pa[0], a1 = pa[1], a2 = pa[2], a3 = pa[3];
      int4 b0 = pb[0], b1 = pb[1], b2 = pb[2], b3 = pb[3];
      ((int4*)sa)[0] = a0; ((int4*)sa)[1] = a1; ((int4*)sa)[2] = a2; ((int4*)sa)[3] = a3;
      ((int4*)sb)[0] = b0; ((int4*)sb)[1] = b1; ((int4*)sb)[2] = b2; ((int4*)sb)[3] = b3;
    }
    __syncthreads();
    #pragma unroll
    for (int kk = 0; kk < BK; kk += 32) {
      int koff = kk + ((lane >> 4) << 3);
      int r16 = lane & 15;
      bf16x8 af[4], bfr[4];
      #pragma unroll
      for (int i = 0; i < 4; i++)
        af[i] = *(const bf16x8*)(As + (wm + i*16 + r16)*LDSS + koff);
      #pragma unroll
      for (int i = 0; i < 4; i++)
        bfr[i] = *(const bf16x8*)(Bs + (wn + i*16 + r16)*LDSS + koff);
      #pragma unroll
      for (int mi = 0; mi < 4; mi++)
        #pragma unroll
        for (int ni = 0; ni < 4; ni++)
          acc[mi][ni] = __builtin_amdgcn_mfma_f32_16x16x32_bf16(af[mi], bfr[ni], acc[mi][ni], 0, 0, 0);
    }
    __syncthreads();
  }

  int quad = lane >> 4, c16 = lane & 15;
  #pragma unroll
  for (int mi = 0; mi < 4; mi++) {
    #pragma unroll
    for (int ni = 0; ni < 4; ni++) {
      #pragma unroll
      for (int r = 0; r < 4; r++) {
        int row = bm0 + wm + mi*16 + quad*4 + r;
        int col = bn0 + wn + ni*16 + c16;
        size_t idx = (size_t)row * N + col;
        float v = acc[mi][ni][r];
        if (bias) v += bias[col];
        if constexpr (EPI == EPI_PLAIN) {
          outF[idx] = v;
        } else if constexpr (EPI == EPI_HID) {
          float e = eluf(v) * rowmask[row];
          outF[idx] = e; outB[idx] = f2b(e);
        } else if constexpr (EPI == EPI_GATE) {
          float gg = sigm(v + aux1[idx]);
          float e = (gg*auxCh[idx] + (1.f-gg)*auxDep[idx]) * rowmask[row];
          outF[idx] = e; outB[idx] = f2b(e);
        } else if constexpr (EPI == EPI_ELU) {
          outF[idx] = eluf(v);
        } else if constexpr (EPI == EPI_ELUMUL) {
          outF[idx] = eluf(v) * aux1[idx];
        }
      }
    }
  }
}

// ---------------- attention: logits -> softmax -> depend (per (b,i)) ----------------
__global__ __launch_bounds__(256) void k_attn(
    const float* __restrict__ head, const float* __restrict__ tail,
    const float* __restrict__ chid, const int* __restrict__ lens,
    float* __restrict__ dep_f, u16* __restrict__ dep_b)
{
  int blk = blockIdx.x;
  int b = blk / SL, i = blk % SL;
  int t = threadIdx.x, lane = t & 63, wave = t >> 6;
  int lenb = lens[b];
  size_t base = (size_t)b * SL * H_;
  const float* hrow = head + base + (size_t)i * H_;
  float4 h0 = ((const float4*)(hrow + lane*8))[0];
  float4 h1 = ((const float4*)(hrow + lane*8))[1];

  __shared__ float sc[SL];
  __shared__ float red[256];

  for (int j = wave; j < SL; j += 4) {
    const float* trow = tail + base + (size_t)j * H_;
    float4 t0 = ((const float4*)trow)[lane*2];
    float4 t1 = ((const float4*)trow)[lane*2+1];
    float p = h0.x*t0.x + h0.y*t0.y + h0.z*t0.z + h0.w*t0.w
            + h1.x*t1.x + h1.y*t1.y + h1.z*t1.z + h1.w*t1.w;
    #pragma unroll
    for (int mk = 32; mk; mk >>= 1) p += __shfl_xor(p, mk, 64);
    if (lane == 0) {
      bool am = (j < i) && (j < lenb);
      sc[j] = am ? p : p - 1e30f;
    }
  }
  __syncthreads();
  float v = (t < SL) ? sc[t] : -3.4e38f;
  red[t] = v; __syncthreads();
  for (int off = 128; off; off >>= 1) { if (t < off) red[t] = fmaxf(red[t], red[t+off]); __syncthreads(); }
  float mx = red[0]; __syncthreads();
  float e = (t < SL) ? expf(v - mx) : 0.f;
  red[t] = e; __syncthreads();
  for (int off = 128; off; off >>= 1) { if (t < off) red[t] += red[t+off]; __syncthreads(); }
  float ssum = red[0];
  __syncthreads();
  if (t < SL) {
    bool am = (t < i) && (t < lenb);
    sc[t] = am ? (e / ssum) : 0.f;
  }
  __syncthreads();
  float d0 = 0.f, d1 = 0.f;
  for (int j = 0; j < SL; j++) {
    float w = sc[j];
    if (w != 0.f) {
      const float* crow = chid + base + (size_t)j * H_;
      d0 += w * crow[t];
      d1 += w * crow[t + 256];
    }
  }
  size_t o = base + (size_t)i * H_ + t;
  dep_f[o] = d0; dep_f[o + 256] = d1;
  dep_b[o] = f2b(d0); dep_b[o + 256] = f2b(d1);
}

// ---------------- map2 -> pool softmax -> out_b = pool*enc (per b) ----------------
__global__ __launch_bounds__(256) void k_pool(
    const float* __restrict__ prod, const float* __restrict__ enc,
    const float* __restrict__ wm2, const float* __restrict__ bm2,
    const int* __restrict__ lens, u16* __restrict__ out_b)
{
  int b = blockIdx.x, t = threadIdx.x;
  int lane = t & 63, wave = t >> 6;
  int lenb = lens[b];
  size_t base = (size_t)b * SL * H_;
  float4 w0 = ((const float4*)(wm2 + lane*8))[0];
  float4 w1 = ((const float4*)(wm2 + lane*8))[1];
  float bm2v = bm2[0];
  __shared__ float m2[SL];
  __shared__ float red[256];
  for (int s = wave; s < SL; s += 4) {
    const float* prow = prod + base + (size_t)s * H_;
    float4 p0 = ((const float4*)prow)[lane*2];
    float4 p1 = ((const float4*)prow)[lane*2+1];
    float p = w0.x*p0.x + w0.y*p0.y + w0.z*p0.z + w0.w*p0.w
            + w1.x*p1.x + w1.y*p1.y + w1.z*p1.z + w1.w*p1.w;
    #pragma unroll
    for (int mk = 32; mk; mk >>= 1) p += __shfl_xor(p, mk, 64);
    if (lane == 0) m2[s] = p + bm2v + ((s < lenb) ? 0.f : -1e30f);
  }
  __syncthreads();
  float v = (t < SL) ? m2[t] : -3.4e38f;
  red[t] = v; __syncthreads();
  for (int off = 128; off; off >>= 1) { if (t < off) red[t] = fmaxf(red[t], red[t+off]); __syncthreads(); }
  float mx = red[0]; __syncthreads();
  float e = (t < SL) ? expf(v - mx) : 0.f;
  red[t] = e; __syncthreads();
  for (int off = 128; off; off >>= 1) { if (t < off) red[t] += red[t+off]; __syncthreads(); }
  float ssum = red[0];
  __syncthreads();
  if (t < SL) m2[t] = (t < lenb) ? (e / ssum) : 0.f;
  __syncthreads();
  for (int idx = t; idx < SL*H_; idx += 256) {
    int s = idx >> 9;
    out_b[base + idx] = f2b(m2[s] * enc[base + idx]);
  }
}

// ---------------- host ----------------
extern "C" void kernel_launch(void* const* d_in, const int* in_sizes, int n_in,
                              void* d_out, int out_size, void* d_ws, size_t ws_size,
                              hipStream_t stream) {
  const int*   cas         = (const int*)d_in[0];
  const int*   tii         = (const int*)d_in[1];
  const float* embedding   = (const float*)d_in[2];
  const float* time_lambda = (const float*)d_in[3];
  const float* w1   = (const float*)d_in[4];
  const float* b1   = (const float*)d_in[5];
  const float* wh   = (const float*)d_in[6];
  const float* bh   = (const float*)d_in[7];
  const float* wt   = (const float*)d_in[8];
  const float* bt   = (const float*)d_in[9];
  const float* wg   = (const float*)d_in[10];
  const float* bg   = (const float*)d_in[11];
  const float* wm1  = (const float*)d_in[12];
  const float* bm1  = (const float*)d_in[13];
  const float* wti  = (const float*)d_in[14];
  const float* bti  = (const float*)d_in[15];
  const float* wm2  = (const float*)d_in[16];
  const float* bm2  = (const float*)d_in[17];
  const float* wout = (const float*)d_in[18];
  const float* bout = (const float*)d_in[19];
  float* outp = (float*)d_out;

  char* ws = (char*)d_ws;
  size_t off = 0;
  auto alloc = [&](size_t sz) -> void* {
    void* p = ws + off; off += (sz + 255) & ~(size_t)255; return p;
  };
  const size_t SZ_F = (size_t)M_ * H_ * 4;  // 13,107,200
  const size_t SZ_B = (size_t)M_ * H_ * 2;  //  6,553,600
  const size_t SZ_W = (size_t)H_ * H_ * 2;  //    524,288

  int*   lens    = (int*)  alloc(128);
  float* rowmask = (float*)alloc((size_t)M_ * 4);
  float* chid_f  = (float*)alloc(SZ_F);
  float* head_f  = (float*)alloc(SZ_F);
  float* tail_f  = (float*)alloc(SZ_F);
  float* dep_f   = (float*)alloc(SZ_F);
  float* gp_f    = (float*)alloc(SZ_F);   // also reused as prod_f after gate
  float* enc_f   = (float*)alloc(SZ_F);
  float* ti_f    = (float*)alloc(SZ_F);
  u16*   chid_b  = (u16*)  alloc(SZ_B);
  u16*   dep_b   = (u16*)  alloc(SZ_B);
  u16*   enc_b   = (u16*)  alloc(SZ_B);
  u16*   tw_b    = (u16*)  alloc(SZ_B);
  u16*   emb_b   = (u16*)  alloc(SZ_B);   // reused as out_b after G1
  u16*   w1T     = (u16*)  alloc(SZ_W);
  u16*   whT     = (u16*)  alloc(SZ_W);
  u16*   wtT     = (u16*)  alloc(SZ_W);
  u16*   wgT0    = (u16*)  alloc(SZ_W);
  u16*   wgT1    = (u16*)  alloc(SZ_W);
  u16*   wm1T    = (u16*)  alloc(SZ_W);
  u16*   wtiT    = (u16*)  alloc(SZ_W);
  u16*   woutT   = (u16*)  alloc((size_t)V_ * H_ * 2);
  float* prod_f  = gp_f;
  u16*   out_b   = emb_b;

  k_lens<<<B_, 256, 0, stream>>>(cas, lens, rowmask);
  k_gather<<<M_, 256, 0, stream>>>(embedding, cas, emb_b);
  k_gather<<<M_, 256, 0, stream>>>(time_lambda, tii, tw_b);

  dim3 tb(32, 8);
  k_transpose<<<dim3(16,16),   tb, 0, stream>>>(w1,  w1T,  512, 512);
  k_transpose<<<dim3(16,16),   tb, 0, stream>>>(wh,  whT,  512, 512);
  k_transpose<<<dim3(16,16),   tb, 0, stream>>>(wt,  wtT,  512, 512);
  k_transpose<<<dim3(16,16),   tb, 0, stream>>>(wg,            wgT0, 512, 512);
  k_transpose<<<dim3(16,16),   tb, 0, stream>>>(wg + 512*512,  wgT1, 512, 512);
  k_transpose<<<dim3(16,16),   tb, 0, stream>>>(wm1, wm1T, 512, 512);
  k_transpose<<<dim3(16,16),   tb, 0, stream>>>(wti, wtiT, 512, 512);
  k_transpose<<<dim3(1000,16), tb, 0, stream>>>(wout, woutT, 512, 32000);

  // G1: cas_hidden = elu(emb@w1 + b1) * mask   (dual f32/bf16)
  k_gemm<EPI_HID><<<200, 256, 0, stream>>>(emb_b, w1T, 4, 50, 512, 512,
      b1, chid_f, chid_b, nullptr, nullptr, nullptr, rowmask);
  // G2/G3: head/tail
  k_gemm<EPI_PLAIN><<<200, 256, 0, stream>>>(chid_b, whT, 4, 50, 512, 512,
      bh, head_f, nullptr, nullptr, nullptr, nullptr, nullptr);
  k_gemm<EPI_PLAIN><<<200, 256, 0, stream>>>(chid_b, wtT, 4, 50, 512, 512,
      bt, tail_f, nullptr, nullptr, nullptr, nullptr, nullptr);
  // attention
  k_attn<<<M_, 256, 0, stream>>>(head_f, tail_f, chid_f, lens, dep_f, dep_b);
  // G4: gp = chid@wg[:512]
  k_gemm<EPI_PLAIN><<<200, 256, 0, stream>>>(chid_b, wgT0, 4, 50, 512, 512,
      nullptr, gp_f, nullptr, nullptr, nullptr, nullptr, nullptr);
  // G5: gate = sigmoid(gp + dep@wg[512:] + bg); enc = (g*ch+(1-g)*dep)*mask
  k_gemm<EPI_GATE><<<200, 256, 0, stream>>>(dep_b, wgT1, 4, 50, 512, 512,
      bg, enc_f, enc_b, gp_f, chid_f, dep_f, rowmask);
  // G6: ti = elu(tw@wti + bti)
  k_gemm<EPI_ELU><<<200, 256, 0, stream>>>(tw_b, wtiT, 4, 50, 512, 512,
      bti, ti_f, nullptr, nullptr, nullptr, nullptr, nullptr);
  // G7: prod = elu(enc@wm1 + bm1) * ti
  k_gemm<EPI_ELUMUL><<<200, 256, 0, stream>>>(enc_b, wm1T, 4, 50, 512, 512,
      bm1, prod_f, nullptr, ti_f, nullptr, nullptr, nullptr);
  // pool softmax + out_b = pool*enc (bf16)
  k_pool<<<B_, 256, 0, stream>>>(prod_f, enc_f, wm2, bm2, lens, out_b);
  // G8: logits_out = out@wout + bout   (6400 x 32000 x 512)
  k_gemm<EPI_PLAIN><<<12500, 256, 0, stream>>>(out_b, woutT, 250, 50, 32000, 512,
      bout, outp, nullptr, nullptr, nullptr, nullptr, nullptr);
}